// Round 2
// baseline (1461.084 us; speedup 1.0000x reference)
//
#include <hip/hip_runtime.h>
#include <math.h>

// Problem dims
#define T_DIM 3
#define B_DIM 2048
#define NIMG  (T_DIM * B_DIM)   // 6144

// ---------------------------------------------------------------------------
// Generic conv 4x4 stride2 pad1 + ReLU over LDS tensors (unpadded [C][H][W]).
// Thread tid handles COB consecutive output channels for NIT positions.
// ---------------------------------------------------------------------------
template<int CIN, int COUT, int IH, int OH, int COB, int NIT>
__device__ __forceinline__ void convtile(const float* __restrict__ gw,
                                         const float* __restrict__ gb,
                                         const float* __restrict__ sin_,
                                         float* __restrict__ sout,
                                         int tid)
{
    constexpr int NCG   = COUT / COB;
    constexpr int P     = OH * OH;
    constexpr int TASKS = P * NCG;
    if (TASKS < 256) { if (tid >= TASKS) return; }

    const int co0 = (tid % NCG) * COB;
    int ohv[NIT], owv[NIT];
#pragma unroll
    for (int k = 0; k < NIT; k++) {
        int pos = (tid + k * 256) / NCG;
        ohv[k] = pos / OH;
        owv[k] = pos % OH;
    }

    float acc[COB][NIT];
#pragma unroll
    for (int j = 0; j < COB; j++) {
        float bv = gb[co0 + j];
#pragma unroll
        for (int k = 0; k < NIT; k++) acc[j][k] = bv;
    }

    for (int ci = 0; ci < CIN; ci++) {
        float wreg[COB][16];
#pragma unroll
        for (int j = 0; j < COB; j++) {
            const float4* wp = (const float4*)(gw + ((co0 + j) * CIN + ci) * 16);
#pragma unroll
            for (int q = 0; q < 4; q++) {
                float4 w4 = wp[q];
                wreg[j][q * 4 + 0] = w4.x;
                wreg[j][q * 4 + 1] = w4.y;
                wreg[j][q * 4 + 2] = w4.z;
                wreg[j][q * 4 + 3] = w4.w;
            }
        }
        const float* ipc = sin_ + ci * IH * IH;
#pragma unroll
        for (int k = 0; k < NIT; k++) {
            const int oh = ohv[k], ow = owv[k];
#pragma unroll
            for (int kh = 0; kh < 4; kh++) {
                const int ih = 2 * oh - 1 + kh;
                if ((unsigned)ih < (unsigned)IH) {
                    const float* rp = ipc + ih * IH;
#pragma unroll
                    for (int kw = 0; kw < 4; kw++) {
                        const int iw = 2 * ow - 1 + kw;
                        if ((unsigned)iw < (unsigned)IH) {
                            const float xv = rp[iw];
#pragma unroll
                            for (int j = 0; j < COB; j++)
                                acc[j][k] = fmaf(xv, wreg[j][kh * 4 + kw], acc[j][k]);
                        }
                    }
                }
            }
        }
    }
#pragma unroll
    for (int j = 0; j < COB; j++) {
#pragma unroll
        for (int k = 0; k < NIT; k++) {
            int pos = (tid + k * 256) / NCG;
            sout[(co0 + j) * P + pos] = fmaxf(acc[j][k], 0.f);
        }
    }
}

// ---------------------------------------------------------------------------
// Kernel 1: conv layers 0..3, one block per image.
// Layer 0 reads the image DIRECTLY from global (L1/L2-served, <=4x reuse per
// pixel) -- no 48 KB LDS staging. LDS = 24 KB (sL0 16K + sL1 8K; l2 output
// reuses sL0) -> ~5-6 blocks/CU instead of 2.
// Layer-0 weights are wave-uniform (all threads do all 4 co) -> SGPR loads.
// ---------------------------------------------------------------------------
__global__ __launch_bounds__(256) void conv03_kernel(
    const float* __restrict__ img,
    const float* __restrict__ w0, const float* __restrict__ b0,
    const float* __restrict__ w1, const float* __restrict__ b1,
    const float* __restrict__ w2, const float* __restrict__ b2,
    const float* __restrict__ w3, const float* __restrict__ b3,
    float* __restrict__ l3out)
{
    __shared__ float sL0[4096];   // l0 out [4][32][32]; later reused for l2 out [16][8][8]
    __shared__ float sL1[2048];   // l1 out [8][16][16]
    const int tid  = threadIdx.x;
    const int gimg = blockIdx.x;          // t*2048 + b
    const int t    = gimg >> 11;
    const float* ib = img + (size_t)gimg * 12288;

    // ---- layer 0: 3x64x64 -> 4x32x32, direct from global ----
    {
        // pos = tid + k*256, k<4 ; all 4 output channels per thread
        int ohv[4], owv[4];
#pragma unroll
        for (int k = 0; k < 4; k++) {
            int pos = tid + k * 256;
            ohv[k] = pos >> 5;
            owv[k] = pos & 31;
        }
        float acc[4][4];   // [co][k]
#pragma unroll
        for (int j = 0; j < 4; j++) {
            float bv = b0[t * 4 + j];
#pragma unroll
            for (int k = 0; k < 4; k++) acc[j][k] = bv;
        }
        for (int ci = 0; ci < 3; ci++) {
            // wave-uniform weight addresses -> scalar loads
            float wreg[4][16];
#pragma unroll
            for (int j = 0; j < 4; j++) {
                const float4* wp = (const float4*)(w0 + t * 192 + (j * 3 + ci) * 16);
#pragma unroll
                for (int q = 0; q < 4; q++) {
                    float4 w4 = wp[q];
                    wreg[j][q * 4 + 0] = w4.x;
                    wreg[j][q * 4 + 1] = w4.y;
                    wreg[j][q * 4 + 2] = w4.z;
                    wreg[j][q * 4 + 3] = w4.w;
                }
            }
            const float* ip = ib + ci * 4096;
#pragma unroll
            for (int k = 0; k < 4; k++) {
                const int oh = ohv[k], ow = owv[k];
#pragma unroll
                for (int kh = 0; kh < 4; kh++) {
                    const int ih = 2 * oh - 1 + kh;
                    if ((unsigned)ih < 64u) {
                        const float* rp = ip + ih * 64;
#pragma unroll
                        for (int kw = 0; kw < 4; kw++) {
                            const int iw = 2 * ow - 1 + kw;
                            if ((unsigned)iw < 64u) {
                                const float xv = rp[iw];
#pragma unroll
                                for (int j = 0; j < 4; j++)
                                    acc[j][k] = fmaf(xv, wreg[j][kh * 4 + kw], acc[j][k]);
                            }
                        }
                    }
                }
            }
        }
#pragma unroll
        for (int j = 0; j < 4; j++)
#pragma unroll
            for (int k = 0; k < 4; k++)
                sL0[j * 1024 + tid + k * 256] = fmaxf(acc[j][k], 0.f);
    }
    __syncthreads();
    convtile<4, 8, 32, 16, 4, 2>(w1 + t * 512,  b1 + t * 8,  sL0, sL1, tid);
    __syncthreads();
    convtile<8, 16, 16, 8, 4, 1>(w2 + t * 2048, b2 + t * 16, sL1, sL0, tid);
    __syncthreads();
    convtile<16, 32, 8, 4, 2, 1>(w3 + t * 8192, b3 + t * 32, sL0,
                                 l3out + (size_t)gimg * 512, tid);
}

// ---------------------------------------------------------------------------
// Kernel 2: conv layers 4..5, 16 images per block.
// ---------------------------------------------------------------------------
__global__ __launch_bounds__(256) void conv45_kernel(
    const float* __restrict__ l3out,
    const float* __restrict__ w4g, const float* __restrict__ b4g,
    const float* __restrict__ w5g, const float* __restrict__ b5g,
    float* __restrict__ feats)
{
    __shared__ float sIn[16 * 516];
    __shared__ float sMid[16 * 260];
    const int tid  = threadIdx.x;
    const int img0 = blockIdx.x << 4;
    const int t    = img0 >> 11;

    {
        const float4* gp = (const float4*)(l3out + (size_t)img0 * 512);
        for (int i = tid; i < 2048; i += 256) {
            int im = i >> 7;
            int d4 = i & 127;
            *(float4*)&sIn[im * 516 + d4 * 4] = gp[i];
        }
    }
    __syncthreads();

    // ---- layer 4: [32,4,4] -> [64,2,2]
    {
        const int ig  = (tid & 3) << 2;
        const int p   = (tid >> 2) & 3;
        const int co0 = (tid >> 4) << 2;
        const int oh = p >> 1, ow = p & 1;
        const float* wt = w4g + t * 32768;
        float acc[4][4];
#pragma unroll
        for (int j = 0; j < 4; j++) {
            float bv = b4g[t * 64 + co0 + j];
#pragma unroll
            for (int m = 0; m < 4; m++) acc[j][m] = bv;
        }
        for (int ci = 0; ci < 32; ci++) {
            float wreg[4][16];
#pragma unroll
            for (int j = 0; j < 4; j++) {
                const float4* wp = (const float4*)(wt + ((co0 + j) * 32 + ci) * 16);
#pragma unroll
                for (int q = 0; q < 4; q++) {
                    float4 w4 = wp[q];
                    wreg[j][q * 4 + 0] = w4.x;
                    wreg[j][q * 4 + 1] = w4.y;
                    wreg[j][q * 4 + 2] = w4.z;
                    wreg[j][q * 4 + 3] = w4.w;
                }
            }
#pragma unroll
            for (int kh = 0; kh < 4; kh++) {
                int ih = 2 * oh - 1 + kh;
                if ((unsigned)ih < 4u) {
#pragma unroll
                    for (int kw = 0; kw < 4; kw++) {
                        int iw = 2 * ow - 1 + kw;
                        if ((unsigned)iw < 4u) {
                            float xv[4];
#pragma unroll
                            for (int m = 0; m < 4; m++)
                                xv[m] = sIn[(ig + m) * 516 + ci * 16 + ih * 4 + iw];
#pragma unroll
                            for (int j = 0; j < 4; j++)
#pragma unroll
                                for (int m = 0; m < 4; m++)
                                    acc[j][m] = fmaf(xv[m], wreg[j][kh * 4 + kw], acc[j][m]);
                        }
                    }
                }
            }
        }
#pragma unroll
        for (int j = 0; j < 4; j++)
#pragma unroll
            for (int m = 0; m < 4; m++)
                sMid[(ig + m) * 260 + (co0 + j) * 4 + p] = fmaxf(acc[j][m], 0.f);
    }
    __syncthreads();

    // ---- layer 5: [64,2,2] -> [128]
    {
        const int ig  = (tid & 3) << 2;
        const int co0 = (tid >> 2) << 1;
        const float* wt = w5g + t * 131072;
        float acc[2][4];
#pragma unroll
        for (int j = 0; j < 2; j++) {
            float bv = b5g[t * 128 + co0 + j];
#pragma unroll
            for (int m = 0; m < 4; m++) acc[j][m] = bv;
        }
        for (int ci = 0; ci < 64; ci++) {
            float wreg[2][4];
#pragma unroll
            for (int j = 0; j < 2; j++) {
                const float* wp = wt + ((co0 + j) * 64 + ci) * 16;
                wreg[j][0] = wp[5];  wreg[j][1] = wp[6];
                wreg[j][2] = wp[9];  wreg[j][3] = wp[10];
            }
#pragma unroll
            for (int q = 0; q < 4; q++) {
#pragma unroll
                for (int m = 0; m < 4; m++) {
                    float xv = sMid[(ig + m) * 260 + ci * 4 + q];
#pragma unroll
                    for (int j = 0; j < 2; j++)
                        acc[j][m] = fmaf(xv, wreg[j][q], acc[j][m]);
                }
            }
        }
#pragma unroll
        for (int j = 0; j < 2; j++)
#pragma unroll
            for (int m = 0; m < 4; m++)
                feats[(size_t)(img0 + ig + m) * 128 + co0 + j] = fmaxf(acc[j][m], 0.f);
    }
}

// ---------------------------------------------------------------------------
// Kernel 3: MLP 128->32->32->64, LSTM(H=20) over T=3, 20 heads 20->32->32->1.
// ---------------------------------------------------------------------------
__device__ __forceinline__ float sigmoidf_(float x) { return 1.f / (1.f + expf(-x)); }

__global__ __launch_bounds__(64) void head_kernel(
    const float* __restrict__ feats,
    const float* __restrict__ mw1, const float* __restrict__ mb1,
    const float* __restrict__ mw2, const float* __restrict__ mb2,
    const float* __restrict__ mw3, const float* __restrict__ mb3,
    const float* __restrict__ wih, const float* __restrict__ whh,
    const float* __restrict__ bih, const float* __restrict__ bhh,
    const float* __restrict__ hw1, const float* __restrict__ hb1,
    const float* __restrict__ hw2, const float* __restrict__ hb2,
    const float* __restrict__ hw3, const float* __restrict__ hb3,
    float* __restrict__ out)
{
    const int b   = blockIdx.x;
    const int tid = threadIdx.x;
    __shared__ float sX[384];
    __shared__ float sH1[96];
    __shared__ float sH2[96];
    __shared__ float sF[192];
    __shared__ float sGates[80];
    __shared__ float sHs[20], sCs[20], sHseq[60];
    __shared__ float sA1[3 * 640];
    __shared__ float sA2[3 * 640];

    for (int i = tid; i < 96; i += 64) {
        int t = i >> 5, d4 = i & 31;
        ((float4*)sX)[i] = ((const float4*)(feats + (size_t)(t * 2048 + b) * 128))[d4];
    }
    __syncthreads();

    if (tid < 32) {
        const float4* wr = (const float4*)(mw1 + tid * 128);
        float a0 = mb1[tid], a1 = a0, a2 = a0;
        for (int d4 = 0; d4 < 32; d4++) {
            float4 w  = wr[d4];
            float4 x0 = ((const float4*)sX)[d4];
            float4 x1 = ((const float4*)sX)[32 + d4];
            float4 x2 = ((const float4*)sX)[64 + d4];
            a0 = fmaf(w.x, x0.x, a0); a0 = fmaf(w.y, x0.y, a0);
            a0 = fmaf(w.z, x0.z, a0); a0 = fmaf(w.w, x0.w, a0);
            a1 = fmaf(w.x, x1.x, a1); a1 = fmaf(w.y, x1.y, a1);
            a1 = fmaf(w.z, x1.z, a1); a1 = fmaf(w.w, x1.w, a1);
            a2 = fmaf(w.x, x2.x, a2); a2 = fmaf(w.y, x2.y, a2);
            a2 = fmaf(w.z, x2.z, a2); a2 = fmaf(w.w, x2.w, a2);
        }
        sH1[tid] = fmaxf(a0, 0.f); sH1[32 + tid] = fmaxf(a1, 0.f); sH1[64 + tid] = fmaxf(a2, 0.f);
    }
    __syncthreads();

    if (tid < 32) {
        const float* wr = mw2 + tid * 32;
        float a0 = mb2[tid], a1 = a0, a2 = a0;
#pragma unroll
        for (int d = 0; d < 32; d++) {
            float w = wr[d];
            a0 = fmaf(w, sH1[d], a0);
            a1 = fmaf(w, sH1[32 + d], a1);
            a2 = fmaf(w, sH1[64 + d], a2);
        }
        sH2[tid] = fmaxf(a0, 0.f); sH2[32 + tid] = fmaxf(a1, 0.f); sH2[64 + tid] = fmaxf(a2, 0.f);
    }
    __syncthreads();

    {
        const float* wr = mw3 + tid * 32;
        float a0 = mb3[tid], a1 = a0, a2 = a0;
#pragma unroll
        for (int d = 0; d < 32; d++) {
            float w = wr[d];
            a0 = fmaf(w, sH2[d], a0);
            a1 = fmaf(w, sH2[32 + d], a1);
            a2 = fmaf(w, sH2[64 + d], a2);
        }
        sF[tid] = a0; sF[64 + tid] = a1; sF[128 + tid] = a2;
    }
    if (tid < 20) { sHs[tid] = 0.f; sCs[tid] = 0.f; }
    __syncthreads();

    for (int t = 0; t < 3; t++) {
        for (int i = tid; i < 80; i += 64) {
            float a = bih[i] + bhh[i];
            const float4* wi = (const float4*)(wih + i * 64);
            const float4* xr = (const float4*)(sF + t * 64);
#pragma unroll
            for (int d4 = 0; d4 < 16; d4++) {
                float4 w = wi[d4]; float4 x = xr[d4];
                a = fmaf(w.x, x.x, a); a = fmaf(w.y, x.y, a);
                a = fmaf(w.z, x.z, a); a = fmaf(w.w, x.w, a);
            }
            const float* wh = whh + i * 20;
#pragma unroll
            for (int d = 0; d < 20; d++) a = fmaf(wh[d], sHs[d], a);
            sGates[i] = a;
        }
        __syncthreads();
        if (tid < 20) {
            float ig = sigmoidf_(sGates[tid]);
            float fg = sigmoidf_(sGates[20 + tid]);
            float g  = tanhf(sGates[40 + tid]);
            float og = sigmoidf_(sGates[60 + tid]);
            float c  = fg * sCs[tid] + ig * g;
            sCs[tid] = c;
            float h = og * tanhf(c);
            sHs[tid] = h;
            sHseq[t * 20 + tid] = h;
        }
        __syncthreads();
    }

    for (int i = tid; i < 640; i += 64) {
        float wrow[20];
        const float4* wr = (const float4*)(hw1 + i * 20);
#pragma unroll
        for (int q = 0; q < 5; q++) {
            float4 w = wr[q];
            wrow[q * 4 + 0] = w.x; wrow[q * 4 + 1] = w.y;
            wrow[q * 4 + 2] = w.z; wrow[q * 4 + 3] = w.w;
        }
        float bv = hb1[i];
        float a0 = bv, a1 = bv, a2 = bv;
#pragma unroll
        for (int d = 0; d < 20; d++) {
            float w = wrow[d];
            a0 = fmaf(w, sHseq[d], a0);
            a1 = fmaf(w, sHseq[20 + d], a1);
            a2 = fmaf(w, sHseq[40 + d], a2);
        }
        sA1[i] = fmaxf(a0, 0.f); sA1[640 + i] = fmaxf(a1, 0.f); sA1[1280 + i] = fmaxf(a2, 0.f);
    }
    __syncthreads();

    for (int i = tid; i < 640; i += 64) {
        int k = i >> 5;
        float wrow[32];
        const float4* wr = (const float4*)(hw2 + i * 32);
#pragma unroll
        for (int q = 0; q < 8; q++) {
            float4 w = wr[q];
            wrow[q * 4 + 0] = w.x; wrow[q * 4 + 1] = w.y;
            wrow[q * 4 + 2] = w.z; wrow[q * 4 + 3] = w.w;
        }
        float bv = hb2[i];
        float a0 = bv, a1 = bv, a2 = bv;
#pragma unroll
        for (int d = 0; d < 32; d++) {
            float w = wrow[d];
            a0 = fmaf(w, sA1[k * 32 + d], a0);
            a1 = fmaf(w, sA1[640 + k * 32 + d], a1);
            a2 = fmaf(w, sA1[1280 + k * 32 + d], a2);
        }
        sA2[i] = fmaxf(a0, 0.f); sA2[640 + i] = fmaxf(a1, 0.f); sA2[1280 + i] = fmaxf(a2, 0.f);
    }
    __syncthreads();

    if (tid < 20) {
        const float* wr = hw3 + tid * 32;
        float bv = hb3[tid];
        float a0 = bv, a1 = bv, a2 = bv;
#pragma unroll
        for (int d = 0; d < 32; d++) {
            float w = wr[d];
            a0 = fmaf(w, sA2[tid * 32 + d], a0);
            a1 = fmaf(w, sA2[640 + tid * 32 + d], a1);
            a2 = fmaf(w, sA2[1280 + tid * 32 + d], a2);
        }
        out[(size_t)(tid * 3 + 0) * 2048 + b] = a0;
        out[(size_t)(tid * 3 + 1) * 2048 + b] = a1;
        out[(size_t)(tid * 3 + 2) * 2048 + b] = a2;
    }
}

// ---------------------------------------------------------------------------
extern "C" void kernel_launch(void* const* d_in, const int* in_sizes, int n_in,
                              void* d_out, int out_size, void* d_ws, size_t ws_size,
                              hipStream_t stream)
{
    const float* img = (const float*)d_in[0];
    const float* ew0 = (const float*)d_in[1];  const float* eb0 = (const float*)d_in[2];
    const float* ew1 = (const float*)d_in[3];  const float* eb1 = (const float*)d_in[4];
    const float* ew2 = (const float*)d_in[5];  const float* eb2 = (const float*)d_in[6];
    const float* ew3 = (const float*)d_in[7];  const float* eb3 = (const float*)d_in[8];
    const float* ew4 = (const float*)d_in[9];  const float* eb4 = (const float*)d_in[10];
    const float* ew5 = (const float*)d_in[11]; const float* eb5 = (const float*)d_in[12];
    const float* mw1 = (const float*)d_in[13]; const float* mb1 = (const float*)d_in[14];
    const float* mw2 = (const float*)d_in[15]; const float* mb2 = (const float*)d_in[16];
    const float* mw3 = (const float*)d_in[17]; const float* mb3 = (const float*)d_in[18];
    const float* wih = (const float*)d_in[19]; const float* whh = (const float*)d_in[20];
    const float* bih = (const float*)d_in[21]; const float* bhh = (const float*)d_in[22];
    const float* hw1 = (const float*)d_in[23]; const float* hb1 = (const float*)d_in[24];
    const float* hw2 = (const float*)d_in[25]; const float* hb2 = (const float*)d_in[26];
    const float* hw3 = (const float*)d_in[27]; const float* hb3 = (const float*)d_in[28];

    float* ws    = (float*)d_ws;
    float* l3out = ws;                          // [6144][512]
    float* feats = ws + (size_t)NIMG * 512;     // [6144][128]

    conv03_kernel<<<NIMG, 256, 0, stream>>>(img, ew0, eb0, ew1, eb1, ew2, eb2,
                                            ew3, eb3, l3out);
    conv45_kernel<<<NIMG / 16, 256, 0, stream>>>(l3out, ew4, eb4, ew5, eb5, feats);
    head_kernel<<<B_DIM, 64, 0, stream>>>(feats, mw1, mb1, mw2, mb2, mw3, mb3,
                                          wih, whh, bih, bhh,
                                          hw1, hb1, hw2, hb2, hw3, hb3,
                                          (float*)d_out);
}

// Round 3
// 1444.049 us; speedup vs baseline: 1.0118x; 1.0118x over previous
//
#include <hip/hip_runtime.h>
#include <math.h>

#define T_DIM 3
#define B_DIM 2048
#define NIMG  (T_DIM * B_DIM)   // 6144

// ---------------------------------------------------------------------------
// Padded-LDS conv 4x4 stride2 pad1 + ReLU. Input tile is [CIN][IPAD][IPAD]
// with IPAD = IH+2 and a ZERO halo (row/col 0 and IPAD-1), so every tap is an
// UNCONDITIONAL LDS read. Tap col base = 2*ow (even) -> each window row is
// two 8B-aligned float2 reads (ds_read_b64). No branches in the inner loop.
// Thread mapping: co-group fastest (tid & (NCG-1)), then position.
// ---------------------------------------------------------------------------
template<int CIN, int COUT, int IPAD, int OH, int COB, int KITER,
         bool TO_GLOBAL, int OPAD>
__device__ __forceinline__ void convpad(const float* __restrict__ gw,
                                        const float* __restrict__ gb,
                                        const float* __restrict__ sin_,
                                        float* __restrict__ outp, int tid)
{
    constexpr int NCG = COUT / COB;
    constexpr int LG  = (NCG == 1 ? 0 : NCG == 2 ? 1 : NCG == 4 ? 2 :
                         NCG == 8 ? 3 : 4);
    constexpr int LGOH = (OH == 4 ? 2 : OH == 8 ? 3 : 4);

    const int co0  = (tid & (NCG - 1)) * COB;
    const int posb = tid >> LG;

    int ohv[KITER], owv[KITER];
#pragma unroll
    for (int kk = 0; kk < KITER; kk++) {
        int pos = posb + kk * (256 >> LG);
        ohv[kk] = pos >> LGOH;
        owv[kk] = pos & (OH - 1);
    }

    float acc[COB][KITER];
#pragma unroll
    for (int j = 0; j < COB; j++) {
        float bv = gb[co0 + j];
#pragma unroll
        for (int kk = 0; kk < KITER; kk++) acc[j][kk] = bv;
    }

    for (int ci = 0; ci < CIN; ci++) {
        float wreg[COB][16];
#pragma unroll
        for (int j = 0; j < COB; j++) {
            const float4* wp = (const float4*)(gw + ((co0 + j) * CIN + ci) * 16);
#pragma unroll
            for (int q = 0; q < 4; q++) {
                float4 w4 = wp[q];
                wreg[j][q * 4 + 0] = w4.x;
                wreg[j][q * 4 + 1] = w4.y;
                wreg[j][q * 4 + 2] = w4.z;
                wreg[j][q * 4 + 3] = w4.w;
            }
        }
#pragma unroll
        for (int kk = 0; kk < KITER; kk++) {
#pragma unroll
            for (int kh = 0; kh < 4; kh++) {
                const int base = (ci * IPAD + 2 * ohv[kk] + kh) * IPAD + 2 * owv[kk];
                float2 a01 = *(const float2*)&sin_[base];
                float2 a23 = *(const float2*)&sin_[base + 2];
#pragma unroll
                for (int j = 0; j < COB; j++) {
                    acc[j][kk] = fmaf(a01.x, wreg[j][kh * 4 + 0], acc[j][kk]);
                    acc[j][kk] = fmaf(a01.y, wreg[j][kh * 4 + 1], acc[j][kk]);
                    acc[j][kk] = fmaf(a23.x, wreg[j][kh * 4 + 2], acc[j][kk]);
                    acc[j][kk] = fmaf(a23.y, wreg[j][kh * 4 + 3], acc[j][kk]);
                }
            }
        }
    }
#pragma unroll
    for (int j = 0; j < COB; j++) {
#pragma unroll
        for (int kk = 0; kk < KITER; kk++) {
            float v = fmaxf(acc[j][kk], 0.f);
            if (TO_GLOBAL)
                outp[(co0 + j) * OH * OH + ohv[kk] * OH + owv[kk]] = v;
            else
                outp[((co0 + j) * OPAD + ohv[kk] + 1) * OPAD + owv[kk] + 1] = v;
        }
    }
}

// Layer 0: reads padded image half [3][34][66], writes sl0 interior.
// Weight addresses are wave-uniform (all lanes do all 4 co) -> scalar loads.
__device__ __forceinline__ void conv0_half(const float* __restrict__ simg,
                                           float* __restrict__ sl0,
                                           const float* __restrict__ w0t,
                                           const float* __restrict__ b0t,
                                           int tid, int store_base)
{
    int ohv[2], owv[2];
#pragma unroll
    for (int k = 0; k < 2; k++) {
        int pos = tid + k * 256;
        ohv[k] = pos >> 5;       // 0..15 (within half)
        owv[k] = pos & 31;
    }
    float acc[4][2];
#pragma unroll
    for (int j = 0; j < 4; j++) {
        float bv = b0t[j];
        acc[j][0] = bv; acc[j][1] = bv;
    }
    for (int ci = 0; ci < 3; ci++) {
        float wreg[4][16];
#pragma unroll
        for (int j = 0; j < 4; j++) {
            const float4* wp = (const float4*)(w0t + (j * 3 + ci) * 16);
#pragma unroll
            for (int q = 0; q < 4; q++) {
                float4 w4 = wp[q];
                wreg[j][q * 4 + 0] = w4.x;
                wreg[j][q * 4 + 1] = w4.y;
                wreg[j][q * 4 + 2] = w4.z;
                wreg[j][q * 4 + 3] = w4.w;
            }
        }
#pragma unroll
        for (int k = 0; k < 2; k++) {
#pragma unroll
            for (int kh = 0; kh < 4; kh++) {
                const int base = (ci * 34 + 2 * ohv[k] + kh) * 66 + 2 * owv[k];
                float2 a01 = *(const float2*)&simg[base];
                float2 a23 = *(const float2*)&simg[base + 2];
#pragma unroll
                for (int j = 0; j < 4; j++) {
                    acc[j][k] = fmaf(a01.x, wreg[j][kh * 4 + 0], acc[j][k]);
                    acc[j][k] = fmaf(a01.y, wreg[j][kh * 4 + 1], acc[j][k]);
                    acc[j][k] = fmaf(a23.x, wreg[j][kh * 4 + 2], acc[j][k]);
                    acc[j][k] = fmaf(a23.y, wreg[j][kh * 4 + 3], acc[j][k]);
                }
            }
        }
    }
#pragma unroll
    for (int j = 0; j < 4; j++)
#pragma unroll
        for (int k = 0; k < 2; k++)
            sl0[(j * 34 + store_base + ohv[k]) * 34 + owv[k] + 1] =
                fmaxf(acc[j][k], 0.f);
}

// ---------------------------------------------------------------------------
// Kernel 1: conv layers 0..3 fused, one block per image. LDS 45.4 KB:
//   simg [3][34][66] (padded image half, staged twice)  = 6732 f
//   sl0  [4][34][34]                                    = 4624 f
//   sl1  [8][18][18]  overlays simg                     = 2592 f
//   sl2  [16][10][10] overlays simg+2592                = 1600 f
// ---------------------------------------------------------------------------
__global__ __launch_bounds__(256, 3) void conv03_kernel(
    const float* __restrict__ img,
    const float* __restrict__ w0, const float* __restrict__ b0,
    const float* __restrict__ w1, const float* __restrict__ b1,
    const float* __restrict__ w2, const float* __restrict__ b2,
    const float* __restrict__ w3, const float* __restrict__ b3,
    float* __restrict__ l3out)
{
    __shared__ float smem[11356];
    float* simg = smem;          // 6732
    float* sl0  = smem + 6732;   // 4624
    float* sl1  = smem;          // 2592 (after simg dead)
    float* sl2  = smem + 2592;   // 1600

    const int tid  = threadIdx.x;
    const int gimg = blockIdx.x;
    const int t    = gimg >> 11;
    const float4* ib4 = (const float4*)(img + (size_t)gimg * 12288);

    // P0: zero simg fully + sl0 borders
    {
        float4 z4 = {0.f, 0.f, 0.f, 0.f};
        float4* s4 = (float4*)simg;
        for (int i = tid; i < 1683; i += 256) s4[i] = z4;
        for (int i = tid; i < 528; i += 256) {
            int ch = i / 132, r = i - ch * 132;
            int row, col;
            if (r < 34)       { row = 0;      col = r; }
            else if (r < 68)  { row = 33;     col = r - 34; }
            else if (r < 100) { row = r - 67; col = 0; }
            else              { row = r - 99; col = 33; }
            sl0[(ch * 34 + row) * 34 + col] = 0.f;
        }
    }
    __syncthreads();

    // P1: stage image rows 0..32 -> simg rows 1..33 (row 0 = zero halo)
    for (int i = tid; i < 1584; i += 256) {
        int ci = i / 528, rem = i - ci * 528;
        int row = rem >> 4, c4 = rem & 15;
        float4 v = ib4[ci * 1024 + row * 16 + c4];
        float* dst = &simg[(ci * 34 + row + 1) * 66 + c4 * 4 + 1];
        dst[0] = v.x; dst[1] = v.y; dst[2] = v.z; dst[3] = v.w;
    }
    __syncthreads();

    // P2: layer0 for oh 0..15
    conv0_half(simg, sl0, w0 + t * 192, b0 + t * 4, tid, 1);
    __syncthreads();

    // P3: re-zero simg row 33 (image row 64 OOB); stage rows 31..63 -> r 0..32
    for (int i = tid; i < 198; i += 256) {
        int ch = i / 66, col = i - ch * 66;
        simg[(ch * 34 + 33) * 66 + col] = 0.f;
    }
    for (int i = tid; i < 1584; i += 256) {
        int ci = i / 528, rem = i - ci * 528;
        int row = rem >> 4, c4 = rem & 15;
        float4 v = ib4[ci * 1024 + (row + 31) * 16 + c4];
        float* dst = &simg[(ci * 34 + row) * 66 + c4 * 4 + 1];
        dst[0] = v.x; dst[1] = v.y; dst[2] = v.z; dst[3] = v.w;
    }
    __syncthreads();

    // P4: layer0 for oh 16..31 (same r = 2*oh'+kh indexing by construction)
    conv0_half(simg, sl0, w0 + t * 192, b0 + t * 4, tid, 17);
    __syncthreads();

    // P5: zero sl1+sl2 borders (simg now dead), then layer1
    for (int i = tid; i < 544; i += 256) {
        int ch = i / 68, r = i - ch * 68;
        int row, col;
        if (r < 18)      { row = 0;      col = r; }
        else if (r < 36) { row = 17;     col = r - 18; }
        else if (r < 52) { row = r - 35; col = 0; }
        else             { row = r - 51; col = 17; }
        sl1[(ch * 18 + row) * 18 + col] = 0.f;
    }
    for (int i = tid; i < 576; i += 256) {
        int ch = i / 36, r = i - ch * 36;
        int row, col;
        if (r < 10)      { row = 0;      col = r; }
        else if (r < 20) { row = 9;      col = r - 10; }
        else if (r < 28) { row = r - 19; col = 0; }
        else             { row = r - 27; col = 9; }
        sl2[(ch * 10 + row) * 10 + col] = 0.f;
    }
    convpad<4, 8, 34, 16, 4, 2, false, 18>(w1 + t * 512, b1 + t * 8,
                                           sl0, sl1, tid);
    __syncthreads();

    // P6: layer2
    convpad<8, 16, 18, 8, 4, 1, false, 10>(w2 + t * 2048, b2 + t * 16,
                                           sl1, sl2, tid);
    __syncthreads();

    // P7: layer3 -> global [co*16 + pos]
    convpad<16, 32, 10, 4, 2, 1, true, 0>(w3 + t * 8192, b3 + t * 32,
                                          sl2, l3out + (size_t)gimg * 512, tid);
}

// ---------------------------------------------------------------------------
// Kernel 2: conv layers 4..5, 8 images per block, padded LDS for layer 4.
//   sIn  [8][32][6][6] pitch 1156/img (bank stagger)  = 9248 f (37 KB)
//   sMid [8][260]                                     = 2080 f
// ---------------------------------------------------------------------------
__global__ __launch_bounds__(256, 3) void conv45_kernel(
    const float* __restrict__ l3out,
    const float* __restrict__ w4g, const float* __restrict__ b4g,
    const float* __restrict__ w5g, const float* __restrict__ b5g,
    float* __restrict__ feats)
{
    __shared__ float sIn[8 * 1156];
    __shared__ float sMid[8 * 260];
    const int tid  = threadIdx.x;
    const int img0 = blockIdx.x << 3;
    const int t    = img0 >> 11;

    // border zeros (disjoint from data cells -> same phase as staging)
    for (int i = tid; i < 5120; i += 256) {
        int u = i / 20, c = i - u * 20;
        int im = u >> 5, ci = u & 31;
        int row, col;
        if (c < 6)       { row = 0;      col = c; }
        else if (c < 12) { row = 5;      col = c - 6; }
        else if (c < 16) { row = c - 11; col = 0; }
        else             { row = c - 15; col = 5; }
        sIn[im * 1156 + ci * 36 + row * 6 + col] = 0.f;
    }
    // stage l3 outputs into padded interior
    for (int i = tid; i < 1024; i += 256) {
        int im = i >> 7, rem = i & 127;
        int co = rem >> 2, h = rem & 3;
        float4 v = ((const float4*)(l3out + (size_t)(img0 + im) * 512))[rem];
        float* dst = &sIn[im * 1156 + co * 36 + (h + 1) * 6 + 1];
        dst[0] = v.x; dst[1] = v.y; dst[2] = v.z; dst[3] = v.w;
    }
    __syncthreads();

    // ---- layer 4: [32][4][4] -> [64][2][2], unconditional b64 taps
    {
        const int pos = tid & 3, cg = (tid >> 2) & 7, im = tid >> 5;
        const int oh = pos >> 1, ow = pos & 1;
        const float* wt = w4g + t * 32768;
#pragma unroll
        for (int k = 0; k < 2; k++) {
            const int co0 = cg * 4 + k * 32;
            float acc[4];
#pragma unroll
            for (int j = 0; j < 4; j++) acc[j] = b4g[t * 64 + co0 + j];
            for (int ci = 0; ci < 32; ci++) {
                float wreg[4][16];
#pragma unroll
                for (int j = 0; j < 4; j++) {
                    const float4* wp = (const float4*)(wt + ((co0 + j) * 32 + ci) * 16);
#pragma unroll
                    for (int q = 0; q < 4; q++) {
                        float4 w4 = wp[q];
                        wreg[j][q * 4 + 0] = w4.x;
                        wreg[j][q * 4 + 1] = w4.y;
                        wreg[j][q * 4 + 2] = w4.z;
                        wreg[j][q * 4 + 3] = w4.w;
                    }
                }
#pragma unroll
                for (int kh = 0; kh < 4; kh++) {
                    const int base = im * 1156 + ci * 36 + (2 * oh + kh) * 6 + 2 * ow;
                    float2 a01 = *(const float2*)&sIn[base];
                    float2 a23 = *(const float2*)&sIn[base + 2];
#pragma unroll
                    for (int j = 0; j < 4; j++) {
                        acc[j] = fmaf(a01.x, wreg[j][kh * 4 + 0], acc[j]);
                        acc[j] = fmaf(a01.y, wreg[j][kh * 4 + 1], acc[j]);
                        acc[j] = fmaf(a23.x, wreg[j][kh * 4 + 2], acc[j]);
                        acc[j] = fmaf(a23.y, wreg[j][kh * 4 + 3], acc[j]);
                    }
                }
            }
#pragma unroll
            for (int j = 0; j < 4; j++)
                sMid[im * 260 + (co0 + j) * 4 + pos] = fmaxf(acc[j], 0.f);
        }
    }
    __syncthreads();

    // ---- layer 5: [64][2][2] -> [128] (taps 5,6,9,10), float4 LDS reads
    {
        const int im = tid >> 5, co0 = (tid & 31) * 4;
        const float* wt = w5g + t * 131072;
        float acc[4];
#pragma unroll
        for (int j = 0; j < 4; j++) acc[j] = b5g[t * 128 + co0 + j];
        for (int ci = 0; ci < 64; ci++) {
            float4 x = *(const float4*)&sMid[im * 260 + ci * 4];
#pragma unroll
            for (int j = 0; j < 4; j++) {
                const float* wp = wt + ((co0 + j) * 64 + ci) * 16;
                float4 wA = *(const float4*)(wp + 4);
                float4 wB = *(const float4*)(wp + 8);
                acc[j] = fmaf(x.x, wA.y, acc[j]);
                acc[j] = fmaf(x.y, wA.z, acc[j]);
                acc[j] = fmaf(x.z, wB.y, acc[j]);
                acc[j] = fmaf(x.w, wB.z, acc[j]);
            }
        }
        float4 o;
        o.x = fmaxf(acc[0], 0.f); o.y = fmaxf(acc[1], 0.f);
        o.z = fmaxf(acc[2], 0.f); o.w = fmaxf(acc[3], 0.f);
        *(float4*)&feats[(size_t)(img0 + im) * 128 + co0] = o;
    }
}

// ---------------------------------------------------------------------------
// Kernel 3: MLP 128->32->32->64, LSTM(H=20) over T=3, 20 heads 20->32->32->1.
// ---------------------------------------------------------------------------
__device__ __forceinline__ float sigmoidf_(float x) { return 1.f / (1.f + expf(-x)); }

__global__ __launch_bounds__(64) void head_kernel(
    const float* __restrict__ feats,
    const float* __restrict__ mw1, const float* __restrict__ mb1,
    const float* __restrict__ mw2, const float* __restrict__ mb2,
    const float* __restrict__ mw3, const float* __restrict__ mb3,
    const float* __restrict__ wih, const float* __restrict__ whh,
    const float* __restrict__ bih, const float* __restrict__ bhh,
    const float* __restrict__ hw1, const float* __restrict__ hb1,
    const float* __restrict__ hw2, const float* __restrict__ hb2,
    const float* __restrict__ hw3, const float* __restrict__ hb3,
    float* __restrict__ out)
{
    const int b   = blockIdx.x;
    const int tid = threadIdx.x;
    __shared__ float sX[384];
    __shared__ float sH1[96];
    __shared__ float sH2[96];
    __shared__ float sF[192];
    __shared__ float sGates[80];
    __shared__ float sHs[20], sCs[20], sHseq[60];
    __shared__ float sA1[3 * 640];
    __shared__ float sA2[3 * 640];

    for (int i = tid; i < 96; i += 64) {
        int t = i >> 5, d4 = i & 31;
        ((float4*)sX)[i] = ((const float4*)(feats + (size_t)(t * 2048 + b) * 128))[d4];
    }
    __syncthreads();

    if (tid < 32) {
        const float4* wr = (const float4*)(mw1 + tid * 128);
        float a0 = mb1[tid], a1 = a0, a2 = a0;
        for (int d4 = 0; d4 < 32; d4++) {
            float4 w  = wr[d4];
            float4 x0 = ((const float4*)sX)[d4];
            float4 x1 = ((const float4*)sX)[32 + d4];
            float4 x2 = ((const float4*)sX)[64 + d4];
            a0 = fmaf(w.x, x0.x, a0); a0 = fmaf(w.y, x0.y, a0);
            a0 = fmaf(w.z, x0.z, a0); a0 = fmaf(w.w, x0.w, a0);
            a1 = fmaf(w.x, x1.x, a1); a1 = fmaf(w.y, x1.y, a1);
            a1 = fmaf(w.z, x1.z, a1); a1 = fmaf(w.w, x1.w, a1);
            a2 = fmaf(w.x, x2.x, a2); a2 = fmaf(w.y, x2.y, a2);
            a2 = fmaf(w.z, x2.z, a2); a2 = fmaf(w.w, x2.w, a2);
        }
        sH1[tid] = fmaxf(a0, 0.f); sH1[32 + tid] = fmaxf(a1, 0.f); sH1[64 + tid] = fmaxf(a2, 0.f);
    }
    __syncthreads();

    if (tid < 32) {
        const float* wr = mw2 + tid * 32;
        float a0 = mb2[tid], a1 = a0, a2 = a0;
#pragma unroll
        for (int d = 0; d < 32; d++) {
            float w = wr[d];
            a0 = fmaf(w, sH1[d], a0);
            a1 = fmaf(w, sH1[32 + d], a1);
            a2 = fmaf(w, sH1[64 + d], a2);
        }
        sH2[tid] = fmaxf(a0, 0.f); sH2[32 + tid] = fmaxf(a1, 0.f); sH2[64 + tid] = fmaxf(a2, 0.f);
    }
    __syncthreads();

    {
        const float* wr = mw3 + tid * 32;
        float a0 = mb3[tid], a1 = a0, a2 = a0;
#pragma unroll
        for (int d = 0; d < 32; d++) {
            float w = wr[d];
            a0 = fmaf(w, sH2[d], a0);
            a1 = fmaf(w, sH2[32 + d], a1);
            a2 = fmaf(w, sH2[64 + d], a2);
        }
        sF[tid] = a0; sF[64 + tid] = a1; sF[128 + tid] = a2;
    }
    if (tid < 20) { sHs[tid] = 0.f; sCs[tid] = 0.f; }
    __syncthreads();

    for (int t = 0; t < 3; t++) {
        for (int i = tid; i < 80; i += 64) {
            float a = bih[i] + bhh[i];
            const float4* wi = (const float4*)(wih + i * 64);
            const float4* xr = (const float4*)(sF + t * 64);
#pragma unroll
            for (int d4 = 0; d4 < 16; d4++) {
                float4 w = wi[d4]; float4 x = xr[d4];
                a = fmaf(w.x, x.x, a); a = fmaf(w.y, x.y, a);
                a = fmaf(w.z, x.z, a); a = fmaf(w.w, x.w, a);
            }
            const float* wh = whh + i * 20;
#pragma unroll
            for (int d = 0; d < 20; d++) a = fmaf(wh[d], sHs[d], a);
            sGates[i] = a;
        }
        __syncthreads();
        if (tid < 20) {
            float ig = sigmoidf_(sGates[tid]);
            float fg = sigmoidf_(sGates[20 + tid]);
            float g  = tanhf(sGates[40 + tid]);
            float og = sigmoidf_(sGates[60 + tid]);
            float c  = fg * sCs[tid] + ig * g;
            sCs[tid] = c;
            float h = og * tanhf(c);
            sHs[tid] = h;
            sHseq[t * 20 + tid] = h;
        }
        __syncthreads();
    }

    for (int i = tid; i < 640; i += 64) {
        float wrow[20];
        const float4* wr = (const float4*)(hw1 + i * 20);
#pragma unroll
        for (int q = 0; q < 5; q++) {
            float4 w = wr[q];
            wrow[q * 4 + 0] = w.x; wrow[q * 4 + 1] = w.y;
            wrow[q * 4 + 2] = w.z; wrow[q * 4 + 3] = w.w;
        }
        float bv = hb1[i];
        float a0 = bv, a1 = bv, a2 = bv;
#pragma unroll
        for (int d = 0; d < 20; d++) {
            float w = wrow[d];
            a0 = fmaf(w, sHseq[d], a0);
            a1 = fmaf(w, sHseq[20 + d], a1);
            a2 = fmaf(w, sHseq[40 + d], a2);
        }
        sA1[i] = fmaxf(a0, 0.f); sA1[640 + i] = fmaxf(a1, 0.f); sA1[1280 + i] = fmaxf(a2, 0.f);
    }
    __syncthreads();

    for (int i = tid; i < 640; i += 64) {
        int k = i >> 5;
        float wrow[32];
        const float4* wr = (const float4*)(hw2 + i * 32);
#pragma unroll
        for (int q = 0; q < 8; q++) {
            float4 w = wr[q];
            wrow[q * 4 + 0] = w.x; wrow[q * 4 + 1] = w.y;
            wrow[q * 4 + 2] = w.z; wrow[q * 4 + 3] = w.w;
        }
        float bv = hb2[i];
        float a0 = bv, a1 = bv, a2 = bv;
#pragma unroll
        for (int d = 0; d < 32; d++) {
            float w = wrow[d];
            a0 = fmaf(w, sA1[k * 32 + d], a0);
            a1 = fmaf(w, sA1[640 + k * 32 + d], a1);
            a2 = fmaf(w, sA1[1280 + k * 32 + d], a2);
        }
        sA2[i] = fmaxf(a0, 0.f); sA2[640 + i] = fmaxf(a1, 0.f); sA2[1280 + i] = fmaxf(a2, 0.f);
    }
    __syncthreads();

    if (tid < 20) {
        const float* wr = hw3 + tid * 32;
        float bv = hb3[tid];
        float a0 = bv, a1 = bv, a2 = bv;
#pragma unroll
        for (int d = 0; d < 32; d++) {
            float w = wr[d];
            a0 = fmaf(w, sA2[tid * 32 + d], a0);
            a1 = fmaf(w, sA2[640 + tid * 32 + d], a1);
            a2 = fmaf(w, sA2[1280 + tid * 32 + d], a2);
        }
        out[(size_t)(tid * 3 + 0) * 2048 + b] = a0;
        out[(size_t)(tid * 3 + 1) * 2048 + b] = a1;
        out[(size_t)(tid * 3 + 2) * 2048 + b] = a2;
    }
}

// ---------------------------------------------------------------------------
extern "C" void kernel_launch(void* const* d_in, const int* in_sizes, int n_in,
                              void* d_out, int out_size, void* d_ws, size_t ws_size,
                              hipStream_t stream)
{
    const float* img = (const float*)d_in[0];
    const float* ew0 = (const float*)d_in[1];  const float* eb0 = (const float*)d_in[2];
    const float* ew1 = (const float*)d_in[3];  const float* eb1 = (const float*)d_in[4];
    const float* ew2 = (const float*)d_in[5];  const float* eb2 = (const float*)d_in[6];
    const float* ew3 = (const float*)d_in[7];  const float* eb3 = (const float*)d_in[8];
    const float* ew4 = (const float*)d_in[9];  const float* eb4 = (const float*)d_in[10];
    const float* ew5 = (const float*)d_in[11]; const float* eb5 = (const float*)d_in[12];
    const float* mw1 = (const float*)d_in[13]; const float* mb1 = (const float*)d_in[14];
    const float* mw2 = (const float*)d_in[15]; const float* mb2 = (const float*)d_in[16];
    const float* mw3 = (const float*)d_in[17]; const float* mb3 = (const float*)d_in[18];
    const float* wih = (const float*)d_in[19]; const float* whh = (const float*)d_in[20];
    const float* bih = (const float*)d_in[21]; const float* bhh = (const float*)d_in[22];
    const float* hw1 = (const float*)d_in[23]; const float* hb1 = (const float*)d_in[24];
    const float* hw2 = (const float*)d_in[25]; const float* hb2 = (const float*)d_in[26];
    const float* hw3 = (const float*)d_in[27]; const float* hb3 = (const float*)d_in[28];

    float* ws    = (float*)d_ws;
    float* l3out = ws;                          // [6144][512]
    float* feats = ws + (size_t)NIMG * 512;     // [6144][128]

    conv03_kernel<<<NIMG, 256, 0, stream>>>(img, ew0, eb0, ew1, eb1, ew2, eb2,
                                            ew3, eb3, l3out);
    conv45_kernel<<<NIMG / 8, 256, 0, stream>>>(l3out, ew4, eb4, ew5, eb5, feats);
    head_kernel<<<B_DIM, 64, 0, stream>>>(feats, mw1, mb1, mw2, mb2, mw3, mb3,
                                          wih, whh, bih, bhh,
                                          hw1, hb1, hw2, hb2, hw3, hb3,
                                          (float*)d_out);
}

// Round 4
// 986.046 us; speedup vs baseline: 1.4818x; 1.4645x over previous
//
#include <hip/hip_runtime.h>
#include <math.h>

#define T_DIM 3
#define B_DIM 2048
#define NIMG  (T_DIM * B_DIM)   // 6144

// ===========================================================================
// Image-minor restructure: activations live in ws as [t][C][H][W][2048] fp32
// (innermost = batch index b). lane = image  =>  coalesced vector loads,
// wave-uniform weight addresses (scalar loads), wave-uniform border checks,
// no LDS, no __syncthreads in any conv kernel.
// ===========================================================================

// ---------------------------------------------------------------------------
// Layer 0: reads NCHW input directly. Taps along iw are consecutive floats,
// so each thread loads its 34-tap window as 8 aligned float4 + 2 edge floats;
// L1 serves the cross-tap reuse (working set ~12 KB/wave). One wave handles
// (t, img-group of 64, oh, half-row of 16 ow), all 4 output channels.
// ---------------------------------------------------------------------------
__global__ __launch_bounds__(256) void conv0_kernel(
    const float* __restrict__ img, const float* __restrict__ w0,
    const float* __restrict__ b0, float* __restrict__ a0)
{
    const int wid  = blockIdx.x * 4 + (threadIdx.x >> 6);
    const int lane = threadIdx.x & 63;
    const int half = wid & 1;
    const int oh   = (wid >> 1) & 31;
    const int g    = (wid >> 6) & 31;
    const int t    = wid >> 11;
    const int im   = g * 64 + lane;
    const size_t ib = ((size_t)t * 2048 + im) * 12288;
    const int ow0  = half * 16;

    float acc[4][16];
#pragma unroll
    for (int j = 0; j < 4; j++) {
        const float bv = b0[t * 4 + j];
#pragma unroll
        for (int k = 0; k < 16; k++) acc[j][k] = bv;
    }
    const float* wt = w0 + t * 192;

    for (int ci = 0; ci < 3; ci++) {
#pragma unroll
        for (int kh = 0; kh < 4; kh++) {
            const int ih = 2 * oh - 1 + kh;
            if ((unsigned)ih >= 64u) continue;           // wave-uniform branch
            const float* rp = img + ib + (size_t)(ci * 64 + ih) * 64 + 2 * ow0;
            // tap[r] = input at iw = 2*ow0 - 1 + r,  r = 0..33
            float tap[34];
#pragma unroll
            for (int q = 0; q < 8; q++)
                *(float4*)&tap[1 + 4 * q] = *(const float4*)(rp + 4 * q);
            tap[0]  = (half == 0) ? 0.f : rp[-1];
            tap[33] = (half == 0) ? rp[32] : 0.f;
            float w_[4][4];
#pragma unroll
            for (int j = 0; j < 4; j++)
#pragma unroll
                for (int kw = 0; kw < 4; kw++)
                    w_[j][kw] = wt[((j * 3 + ci) * 4 + kh) * 4 + kw]; // uniform
#pragma unroll
            for (int jj = 0; jj < 16; jj++)
#pragma unroll
                for (int kw = 0; kw < 4; kw++) {
                    const float x = tap[2 * jj + kw];
#pragma unroll
                    for (int j = 0; j < 4; j++)
                        acc[j][jj] = fmaf(x, w_[j][kw], acc[j][jj]);
                }
        }
    }
    const size_t ob0 = ((size_t)(t * 4096 + oh * 32 + ow0)) * 2048 + im;
#pragma unroll
    for (int j = 0; j < 4; j++)
#pragma unroll
        for (int k = 0; k < 16; k++)
            a0[ob0 + ((size_t)j * 1024 + k) * 2048] = fmaxf(acc[j][k], 0.f);
}

// ---------------------------------------------------------------------------
// Generic mid conv (img-minor in AND out). Wave = (t, img-grp, co-grp, oh),
// full output row in registers. Border taps are compile-time zeros.
// ---------------------------------------------------------------------------
template<int CIN, int COUT, int IH, int OH, int CB>
__device__ __forceinline__ void convmid(
    const float* __restrict__ in, const float* __restrict__ gw,
    const float* __restrict__ gb, float* __restrict__ out,
    int t, int cg, int oh, int im)
{
    const int co0 = cg * CB;
    float acc[CB][OH];
#pragma unroll
    for (int j = 0; j < CB; j++) {
        const float bv = gb[t * COUT + co0 + j];
#pragma unroll
        for (int k = 0; k < OH; k++) acc[j][k] = bv;
    }
    const float* wt = gw + ((size_t)t * COUT + co0) * CIN * 16;
    const size_t inb = ((size_t)t * CIN) * (IH * IH) * 2048 + im;

#pragma unroll 4
    for (int ci = 0; ci < CIN; ci++) {
#pragma unroll
        for (int kh = 0; kh < 4; kh++) {
            const int ih = 2 * oh - 1 + kh;
            if ((unsigned)ih >= (unsigned)IH) continue;  // wave-uniform
            const float* rp = in + inb + (size_t)(ci * IH + ih) * IH * 2048;
            float tap[IH + 2];
            tap[0] = 0.f; tap[IH + 1] = 0.f;
#pragma unroll
            for (int iw = 0; iw < IH; iw++) tap[iw + 1] = rp[(size_t)iw * 2048];
            float w_[CB][4];
#pragma unroll
            for (int j = 0; j < CB; j++)
#pragma unroll
                for (int kw = 0; kw < 4; kw++)
                    w_[j][kw] = wt[((size_t)j * CIN + ci) * 16 + kh * 4 + kw];
#pragma unroll
            for (int ow = 0; ow < OH; ow++)
#pragma unroll
                for (int kw = 0; kw < 4; kw++) {
                    const float x = tap[2 * ow + kw];
#pragma unroll
                    for (int j = 0; j < CB; j++)
                        acc[j][ow] = fmaf(x, w_[j][kw], acc[j][ow]);
                }
        }
    }
    const size_t ob = ((size_t)(t * COUT + co0) * OH * OH + (size_t)oh * OH) * 2048 + im;
#pragma unroll
    for (int j = 0; j < CB; j++)
#pragma unroll
        for (int k = 0; k < OH; k++)
            out[ob + ((size_t)j * OH * OH + k) * 2048] = fmaxf(acc[j][k], 0.f);
}

__global__ __launch_bounds__(256) void conv1_kernel(
    const float* __restrict__ a0, const float* __restrict__ w,
    const float* __restrict__ b, float* __restrict__ a1)
{
    const int wid = blockIdx.x * 4 + (threadIdx.x >> 6);
    const int lane = threadIdx.x & 63;
    const int oh = wid & 15, cg = (wid >> 4) & 1, g = (wid >> 5) & 31, t = wid >> 10;
    convmid<4, 8, 32, 16, 4>(a0, w, b, a1, t, cg, oh, g * 64 + lane);
}

__global__ __launch_bounds__(256) void conv2_kernel(
    const float* __restrict__ a1, const float* __restrict__ w,
    const float* __restrict__ b, float* __restrict__ a2)
{
    const int wid = blockIdx.x * 4 + (threadIdx.x >> 6);
    const int lane = threadIdx.x & 63;
    const int oh = wid & 7, cg = (wid >> 3) & 3, g = (wid >> 5) & 31, t = wid >> 10;
    convmid<8, 16, 16, 8, 4>(a1, w, b, a2, t, cg, oh, g * 64 + lane);
}

__global__ __launch_bounds__(256) void conv3_kernel(
    const float* __restrict__ a2, const float* __restrict__ w,
    const float* __restrict__ b, float* __restrict__ a3)
{
    const int wid = blockIdx.x * 4 + (threadIdx.x >> 6);
    const int lane = threadIdx.x & 63;
    const int oh = wid & 3, cg = (wid >> 2) & 3, g = (wid >> 4) & 31, t = wid >> 9;
    convmid<16, 32, 8, 4, 8>(a2, w, b, a3, t, cg, oh, g * 64 + lane);
}

// ---------------------------------------------------------------------------
// Layer 4: [32][4][4] -> [64][2][2]. Wave = (t, img-grp, co-grp of 8),
// all 4 output positions in-thread; OOB taps skipped at compile time.
// ---------------------------------------------------------------------------
__global__ __launch_bounds__(256) void conv4_kernel(
    const float* __restrict__ a3, const float* __restrict__ w4,
    const float* __restrict__ b4, float* __restrict__ a4)
{
    const int wid = blockIdx.x * 4 + (threadIdx.x >> 6);
    const int lane = threadIdx.x & 63;
    const int cg = wid & 7, g = (wid >> 3) & 31, t = wid >> 8;
    const int im = g * 64 + lane;
    const int co0 = cg * 8;

    float acc[8][4];
#pragma unroll
    for (int j = 0; j < 8; j++) {
        const float bv = b4[t * 64 + co0 + j];
#pragma unroll
        for (int p = 0; p < 4; p++) acc[j][p] = bv;
    }
    const float* wt = w4 + ((size_t)t * 64 + co0) * 32 * 16;
    const size_t inb = ((size_t)t * 32) * 16 * 2048 + im;

    for (int ci = 0; ci < 32; ci++) {
        float tin[16];
#pragma unroll
        for (int p = 0; p < 16; p++)
            tin[p] = a3[inb + ((size_t)ci * 16 + p) * 2048];
#pragma unroll
        for (int kh = 0; kh < 4; kh++)
#pragma unroll
            for (int oh = 0; oh < 2; oh++) {
                const int ih = 2 * oh - 1 + kh;
                if (ih < 0 || ih > 3) continue;          // compile-time
#pragma unroll
                for (int ow = 0; ow < 2; ow++)
#pragma unroll
                    for (int kw = 0; kw < 4; kw++) {
                        const int iw = 2 * ow - 1 + kw;
                        if (iw < 0 || iw > 3) continue;  // compile-time
                        const float x = tin[ih * 4 + iw];
#pragma unroll
                        for (int j = 0; j < 8; j++)
                            acc[j][oh * 2 + ow] = fmaf(
                                x, wt[((size_t)j * 32 + ci) * 16 + kh * 4 + kw],
                                acc[j][oh * 2 + ow]);
                    }
            }
    }
#pragma unroll
    for (int j = 0; j < 8; j++)
#pragma unroll
        for (int p = 0; p < 4; p++)
            a4[(((size_t)t * 64 + co0 + j) * 4 + p) * 2048 + im] =
                fmaxf(acc[j][p], 0.f);
}

// ---------------------------------------------------------------------------
// Layer 5: [64][2][2] -> [128]. Only taps (1,1),(1,2),(2,1),(2,2) are valid.
// ---------------------------------------------------------------------------
__global__ __launch_bounds__(256) void conv5_kernel(
    const float* __restrict__ a4, const float* __restrict__ w5,
    const float* __restrict__ b5, float* __restrict__ feats)
{
    const int wid = blockIdx.x * 4 + (threadIdx.x >> 6);
    const int lane = threadIdx.x & 63;
    const int cg = wid & 15, g = (wid >> 4) & 31, t = wid >> 9;
    const int im = g * 64 + lane;
    const int co0 = cg * 8;

    float acc[8];
#pragma unroll
    for (int j = 0; j < 8; j++) acc[j] = b5[t * 128 + co0 + j];
    const float* wt = w5 + ((size_t)t * 128 + co0) * 64 * 16;
    const size_t inb = ((size_t)t * 64) * 4 * 2048 + im;

#pragma unroll 4
    for (int ci = 0; ci < 64; ci++) {
        const float x0 = a4[inb + ((size_t)ci * 4 + 0) * 2048];
        const float x1 = a4[inb + ((size_t)ci * 4 + 1) * 2048];
        const float x2 = a4[inb + ((size_t)ci * 4 + 2) * 2048];
        const float x3 = a4[inb + ((size_t)ci * 4 + 3) * 2048];
#pragma unroll
        for (int j = 0; j < 8; j++) {
            const size_t wb = ((size_t)j * 64 + ci) * 16;
            acc[j] = fmaf(x0, wt[wb + 5],  acc[j]);
            acc[j] = fmaf(x1, wt[wb + 6],  acc[j]);
            acc[j] = fmaf(x2, wt[wb + 9],  acc[j]);
            acc[j] = fmaf(x3, wt[wb + 10], acc[j]);
        }
    }
#pragma unroll
    for (int j = 0; j < 8; j++)
        feats[((size_t)t * 128 + co0 + j) * 2048 + im] = fmaxf(acc[j], 0.f);
}

// ---------------------------------------------------------------------------
// Kernel 3: MLP 128->32->32->64, LSTM(H=20) over T=3, 20 heads 20->32->32->1.
// feats is now img-minor: feats[(t*128+c)*2048 + b].
// ---------------------------------------------------------------------------
__device__ __forceinline__ float sigmoidf_(float x) { return 1.f / (1.f + expf(-x)); }

__global__ __launch_bounds__(64) void head_kernel(
    const float* __restrict__ feats,
    const float* __restrict__ mw1, const float* __restrict__ mb1,
    const float* __restrict__ mw2, const float* __restrict__ mb2,
    const float* __restrict__ mw3, const float* __restrict__ mb3,
    const float* __restrict__ wih, const float* __restrict__ whh,
    const float* __restrict__ bih, const float* __restrict__ bhh,
    const float* __restrict__ hw1, const float* __restrict__ hb1,
    const float* __restrict__ hw2, const float* __restrict__ hb2,
    const float* __restrict__ hw3, const float* __restrict__ hb3,
    float* __restrict__ out)
{
    const int b   = blockIdx.x;
    const int tid = threadIdx.x;
    __shared__ float sX[384];
    __shared__ float sH1[96];
    __shared__ float sH2[96];
    __shared__ float sF[192];
    __shared__ float sGates[80];
    __shared__ float sHs[20], sCs[20], sHseq[60];
    __shared__ float sA1[3 * 640];
    __shared__ float sA2[3 * 640];

    for (int i = tid; i < 384; i += 64)
        sX[i] = feats[(size_t)i * 2048 + b];
    __syncthreads();

    if (tid < 32) {
        const float4* wr = (const float4*)(mw1 + tid * 128);
        float a0 = mb1[tid], a1 = a0, a2 = a0;
        for (int d4 = 0; d4 < 32; d4++) {
            float4 w  = wr[d4];
            float4 x0 = ((const float4*)sX)[d4];
            float4 x1 = ((const float4*)sX)[32 + d4];
            float4 x2 = ((const float4*)sX)[64 + d4];
            a0 = fmaf(w.x, x0.x, a0); a0 = fmaf(w.y, x0.y, a0);
            a0 = fmaf(w.z, x0.z, a0); a0 = fmaf(w.w, x0.w, a0);
            a1 = fmaf(w.x, x1.x, a1); a1 = fmaf(w.y, x1.y, a1);
            a1 = fmaf(w.z, x1.z, a1); a1 = fmaf(w.w, x1.w, a1);
            a2 = fmaf(w.x, x2.x, a2); a2 = fmaf(w.y, x2.y, a2);
            a2 = fmaf(w.z, x2.z, a2); a2 = fmaf(w.w, x2.w, a2);
        }
        sH1[tid] = fmaxf(a0, 0.f); sH1[32 + tid] = fmaxf(a1, 0.f); sH1[64 + tid] = fmaxf(a2, 0.f);
    }
    __syncthreads();

    if (tid < 32) {
        const float* wr = mw2 + tid * 32;
        float a0 = mb2[tid], a1 = a0, a2 = a0;
#pragma unroll
        for (int d = 0; d < 32; d++) {
            float w = wr[d];
            a0 = fmaf(w, sH1[d], a0);
            a1 = fmaf(w, sH1[32 + d], a1);
            a2 = fmaf(w, sH1[64 + d], a2);
        }
        sH2[tid] = fmaxf(a0, 0.f); sH2[32 + tid] = fmaxf(a1, 0.f); sH2[64 + tid] = fmaxf(a2, 0.f);
    }
    __syncthreads();

    {
        const float* wr = mw3 + tid * 32;
        float a0 = mb3[tid], a1 = a0, a2 = a0;
#pragma unroll
        for (int d = 0; d < 32; d++) {
            float w = wr[d];
            a0 = fmaf(w, sH2[d], a0);
            a1 = fmaf(w, sH2[32 + d], a1);
            a2 = fmaf(w, sH2[64 + d], a2);
        }
        sF[tid] = a0; sF[64 + tid] = a1; sF[128 + tid] = a2;
    }
    if (tid < 20) { sHs[tid] = 0.f; sCs[tid] = 0.f; }
    __syncthreads();

    for (int t = 0; t < 3; t++) {
        for (int i = tid; i < 80; i += 64) {
            float a = bih[i] + bhh[i];
            const float4* wi = (const float4*)(wih + i * 64);
            const float4* xr = (const float4*)(sF + t * 64);
#pragma unroll
            for (int d4 = 0; d4 < 16; d4++) {
                float4 w = wi[d4]; float4 x = xr[d4];
                a = fmaf(w.x, x.x, a); a = fmaf(w.y, x.y, a);
                a = fmaf(w.z, x.z, a); a = fmaf(w.w, x.w, a);
            }
            const float* wh = whh + i * 20;
#pragma unroll
            for (int d = 0; d < 20; d++) a = fmaf(wh[d], sHs[d], a);
            sGates[i] = a;
        }
        __syncthreads();
        if (tid < 20) {
            float ig = sigmoidf_(sGates[tid]);
            float fg = sigmoidf_(sGates[20 + tid]);
            float g  = tanhf(sGates[40 + tid]);
            float og = sigmoidf_(sGates[60 + tid]);
            float c  = fg * sCs[tid] + ig * g;
            sCs[tid] = c;
            float h = og * tanhf(c);
            sHs[tid] = h;
            sHseq[t * 20 + tid] = h;
        }
        __syncthreads();
    }

    for (int i = tid; i < 640; i += 64) {
        float wrow[20];
        const float4* wr = (const float4*)(hw1 + i * 20);
#pragma unroll
        for (int q = 0; q < 5; q++) {
            float4 w = wr[q];
            wrow[q * 4 + 0] = w.x; wrow[q * 4 + 1] = w.y;
            wrow[q * 4 + 2] = w.z; wrow[q * 4 + 3] = w.w;
        }
        float bv = hb1[i];
        float a0 = bv, a1 = bv, a2 = bv;
#pragma unroll
        for (int d = 0; d < 20; d++) {
            float w = wrow[d];
            a0 = fmaf(w, sHseq[d], a0);
            a1 = fmaf(w, sHseq[20 + d], a1);
            a2 = fmaf(w, sHseq[40 + d], a2);
        }
        sA1[i] = fmaxf(a0, 0.f); sA1[640 + i] = fmaxf(a1, 0.f); sA1[1280 + i] = fmaxf(a2, 0.f);
    }
    __syncthreads();

    for (int i = tid; i < 640; i += 64) {
        int k = i >> 5;
        float wrow[32];
        const float4* wr = (const float4*)(hw2 + i * 32);
#pragma unroll
        for (int q = 0; q < 8; q++) {
            float4 w = wr[q];
            wrow[q * 4 + 0] = w.x; wrow[q * 4 + 1] = w.y;
            wrow[q * 4 + 2] = w.z; wrow[q * 4 + 3] = w.w;
        }
        float bv = hb2[i];
        float a0 = bv, a1 = bv, a2 = bv;
#pragma unroll
        for (int d = 0; d < 32; d++) {
            float w = wrow[d];
            a0 = fmaf(w, sA1[k * 32 + d], a0);
            a1 = fmaf(w, sA1[640 + k * 32 + d], a1);
            a2 = fmaf(w, sA1[1280 + k * 32 + d], a2);
        }
        sA2[i] = fmaxf(a0, 0.f); sA2[640 + i] = fmaxf(a1, 0.f); sA2[1280 + i] = fmaxf(a2, 0.f);
    }
    __syncthreads();

    if (tid < 20) {
        const float* wr = hw3 + tid * 32;
        float bv = hb3[tid];
        float a0 = bv, a1 = bv, a2 = bv;
#pragma unroll
        for (int d = 0; d < 32; d++) {
            float w = wr[d];
            a0 = fmaf(w, sA2[tid * 32 + d], a0);
            a1 = fmaf(w, sA2[640 + tid * 32 + d], a1);
            a2 = fmaf(w, sA2[1280 + tid * 32 + d], a2);
        }
        out[(size_t)(tid * 3 + 0) * 2048 + b] = a0;
        out[(size_t)(tid * 3 + 1) * 2048 + b] = a1;
        out[(size_t)(tid * 3 + 2) * 2048 + b] = a2;
    }
}

// ---------------------------------------------------------------------------
extern "C" void kernel_launch(void* const* d_in, const int* in_sizes, int n_in,
                              void* d_out, int out_size, void* d_ws, size_t ws_size,
                              hipStream_t stream)
{
    const float* img = (const float*)d_in[0];
    const float* ew0 = (const float*)d_in[1];  const float* eb0 = (const float*)d_in[2];
    const float* ew1 = (const float*)d_in[3];  const float* eb1 = (const float*)d_in[4];
    const float* ew2 = (const float*)d_in[5];  const float* eb2 = (const float*)d_in[6];
    const float* ew3 = (const float*)d_in[7];  const float* eb3 = (const float*)d_in[8];
    const float* ew4 = (const float*)d_in[9];  const float* eb4 = (const float*)d_in[10];
    const float* ew5 = (const float*)d_in[11]; const float* eb5 = (const float*)d_in[12];
    const float* mw1 = (const float*)d_in[13]; const float* mb1 = (const float*)d_in[14];
    const float* mw2 = (const float*)d_in[15]; const float* mb2 = (const float*)d_in[16];
    const float* mw3 = (const float*)d_in[17]; const float* mb3 = (const float*)d_in[18];
    const float* wih = (const float*)d_in[19]; const float* whh = (const float*)d_in[20];
    const float* bih = (const float*)d_in[21]; const float* bhh = (const float*)d_in[22];
    const float* hw1 = (const float*)d_in[23]; const float* hb1 = (const float*)d_in[24];
    const float* hw2 = (const float*)d_in[25]; const float* hb2 = (const float*)d_in[26];
    const float* hw3 = (const float*)d_in[27]; const float* hb3 = (const float*)d_in[28];

    // ws layout (floats), with buffer reuse:
    //   A: 25,165,824 f (a0 [3][4][32][32][2048]; later a2, then a4)
    //   B: 12,582,912 f (a1 [3][8][16][16][2048]; later a3)
    //   C:    786,432 f (feats [3][128][2048])
    // total 154.1 MB
    float* A = (float*)d_ws;
    float* B = A + 25165824;
    float* C = B + 12582912;

    conv0_kernel<<<1536, 256, 0, stream>>>(img, ew0, eb0, A);
    conv1_kernel<<< 768, 256, 0, stream>>>(A, ew1, eb1, B);
    conv2_kernel<<< 768, 256, 0, stream>>>(B, ew2, eb2, A);
    conv3_kernel<<< 384, 256, 0, stream>>>(A, ew3, eb3, B);
    conv4_kernel<<< 192, 256, 0, stream>>>(B, ew4, eb4, A);
    conv5_kernel<<< 384, 256, 0, stream>>>(A, ew5, eb5, C);
    head_kernel<<<B_DIM, 64, 0, stream>>>(C, mw1, mb1, mw2, mb2, mw3, mb3,
                                          wih, whh, bih, bhh,
                                          hw1, hb1, hw2, hb2, hw3, hb3,
                                          (float*)d_out);
}